// Round 3
// baseline (910.228 us; speedup 1.0000x reference)
//
#include <hip/hip_runtime.h>
#include <hip/hip_cooperative_groups.h>

namespace cg = cooperative_groups;

typedef __attribute__((ext_vector_type(8))) short bf16x8;
typedef __attribute__((ext_vector_type(16))) float f32x16;

#define KC 64
#define LDST 72

// ws layout (floats): ssum[8*128] @0, ssq[8*128] @1024, quad[8] @2048,
// lin[8] @2056, Z2[1] @2064
constexpr int ZERO_COUNT = 1024 + 1024 + 8 + 8 + 1;  // 2065

__device__ inline ushort f2bf(float f) {
    unsigned u = __float_as_uint(f);
    return (ushort)((u + 0x7FFFu + ((u >> 16) & 1u)) >> 16);
}

__global__ __launch_bounds__(256) void zero_kernel(float* __restrict__ p, int n) {
    int i = blockIdx.x * 256 + threadIdx.x;
    if (i < n) p[i] = 0.0f;
}

// One block per batch element, 512 threads = 8 waves, 1 block/CU.
// Phase A: BB[b] k-reduce -> 32 regs/thread (BBsum never hits global).
// Phase B: bf16 MFMA Gram of B[b] -> G kept in MFMA accumulators; c -> LDS.
// Phase C: Bz reduce, z^2 partial, x_est=0.
// Phase D: 8 layers; grid.sync per layer for BatchNorm stats; losses at end.
__global__ __launch_bounds__(512, 2) void scnet_fused(
    const float* __restrict__ BB, const float* __restrict__ zB,
    const float* __restrict__ z, const float* __restrict__ Bmat,
    const float* __restrict__ Mask,
    const float* __restrict__ w1, const float* __restrict__ b1,
    const float* __restrict__ w2, const float* __restrict__ b2,
    const float* __restrict__ gamma, const float* __restrict__ beta,
    float* __restrict__ ssum, float* __restrict__ ssq,
    float* __restrict__ quad, float* __restrict__ lin,
    float* __restrict__ Z2, float* __restrict__ dout)
{
    cg::grid_group grid = cg::this_grid();

    const int b = blockIdx.x;
    const int t = threadIdx.x;
    const int w = t >> 6;          // wave 0..7
    const int lane = t & 63;
    const int l31 = lane & 31;
    const int kg = lane >> 5;

    __shared__ ushort As[2][128 * LDST];   // 36 KiB staging
    __shared__ ushort zsb[2][64];
    __shared__ float xs[128];
    __shared__ float part[8][128];
    __shared__ float Bz_lds[128];
    __shared__ float c_lds[128];
    __shared__ float redq[8], redl[8];

    // ---------- Phase A: BBreg[i] = sum_k BB[b, w*16+(i&15), (i>>4)*64+lane, k]
    float BBreg[32];
    {
        const float* BBb = BB + (size_t)b * (128 * 128 * 32);
#pragma unroll
        for (int i = 0; i < 32; ++i) {
            const int n = w * 16 + (i & 15);
            const int m = (i >> 4) * 64 + lane;
            const float4* p = (const float4*)(BBb + ((size_t)n * 128 + m) * 32);
            float s = 0.f;
#pragma unroll
            for (int j = 0; j < 8; ++j) { float4 v = p[j]; s += v.x + v.y + v.z + v.w; }
            BBreg[i] = s;
        }
    }

    // ---------- Phase B: Gram. Wave w owns 32x32 tiles T=2w (wr,wc0) and 2w+1 (wr,wc1).
    const int wr = w >> 1;
    const int wc0 = (2 * w) & 3;
    const int wc1 = wc0 + 1;
    const bool dg = (wr == wc0) || (wr == wc1);   // this wave holds a diagonal tile
    f32x16 acc0, acc1, cacc;
#pragma unroll
    for (int i = 0; i < 16; ++i) { acc0[i] = 0.f; acc1[i] = 0.f; cacc[i] = 0.f; }

    const float* Bb = Bmat + (size_t)b * (128 * 4096);
    const float* zb = z + (size_t)b * 4096;

    const int foff_a  = (wr  * 32 + l31) * LDST + kg * 8;
    const int foff_b0 = (wc0 * 32 + l31) * LDST + kg * 8;
    const int foff_b1 = (wc1 * 32 + l31) * LDST + kg * 8;

    float4 pre[4];
#pragma unroll
    for (int i = 0; i < 4; ++i) {
        int f = t + 512 * i;
        int r = f >> 4, c4 = f & 15;
        pre[i] = *(const float4*)(Bb + (size_t)r * 4096 + c4 * 4);
    }
    float4 zpre;
    if (t < 16) zpre = *(const float4*)(zb + t * 4);

    for (int ch = 0; ch < 64; ++ch) {
        const int cur = ch & 1;
#pragma unroll
        for (int i = 0; i < 4; ++i) {
            int f = t + 512 * i;
            int r = f >> 4, c4 = f & 15;
            *(ushort4*)&As[cur][r * LDST + c4 * 4] =
                make_ushort4(f2bf(pre[i].x), f2bf(pre[i].y), f2bf(pre[i].z), f2bf(pre[i].w));
        }
        if (t < 16)
            *(ushort4*)&zsb[cur][t * 4] =
                make_ushort4(f2bf(zpre.x), f2bf(zpre.y), f2bf(zpre.z), f2bf(zpre.w));
        __syncthreads();
        if (ch < 63) {
            const float* src = Bb + (ch + 1) * KC;
#pragma unroll
            for (int i = 0; i < 4; ++i) {
                int f = t + 512 * i;
                int r = f >> 4, c4 = f & 15;
                pre[i] = *(const float4*)(src + (size_t)r * 4096 + c4 * 4);
            }
            if (t < 16) zpre = *(const float4*)(zb + (ch + 1) * KC + t * 4);
        }
#pragma unroll
        for (int ks = 0; ks < 4; ++ks) {
            bf16x8 a   = *(const bf16x8*)&As[cur][foff_a + ks * 16];
            bf16x8 bf0 = *(const bf16x8*)&As[cur][foff_b0 + ks * 16];
            bf16x8 bf1 = *(const bf16x8*)&As[cur][foff_b1 + ks * 16];
            acc0 = __builtin_amdgcn_mfma_f32_32x32x16_bf16(a, bf0, acc0, 0, 0, 0);
            acc1 = __builtin_amdgcn_mfma_f32_32x32x16_bf16(a, bf1, acc1, 0, 0, 0);
            if (dg) {
                bf16x8 zf;
#pragma unroll
                for (int i = 0; i < 8; ++i) zf[i] = 0;
                if (l31 == 0) zf = *(const bf16x8*)&zsb[cur][ks * 16 + kg * 8];
                cacc = __builtin_amdgcn_mfma_f32_32x32x16_bf16(a, zf, cacc, 0, 0, 0);
            }
        }
        // no trailing barrier: next iter writes the OTHER buffer; reuse of this
        // buffer (ch+2) is separated by the ch+1 barrier.
    }

    // c epilogue: diag-tile column 0 holds c rows (C/D: col=l31, row below)
    if (dg && l31 == 0) {
#pragma unroll
        for (int r = 0; r < 16; ++r) {
            int row = wr * 32 + (r & 3) + 8 * (r >> 2) + 4 * kg;
            c_lds[row] = cacc[r];
        }
    }

    // ---------- Phase C: Bz, z^2, x_est = 0
    if (t < 128) {
        const float4* p = (const float4*)(zB + (size_t)b * 4096 + (size_t)t * 32);
        float s = 0.f;
#pragma unroll
        for (int j = 0; j < 8; ++j) { float4 v = p[j]; s += v.x + v.y + v.z + v.w; }
        Bz_lds[t] = s;
        xs[t] = 0.f;
    }
    {
        const float4* z4 = (const float4*)zb;
        float4 v0 = z4[t * 2], v1 = z4[t * 2 + 1];
        float s = v0.x * v0.x + v0.y * v0.y + v0.z * v0.z + v0.w * v0.w
                + v1.x * v1.x + v1.y * v1.y + v1.z * v1.z + v1.w * v1.w;
#pragma unroll
        for (int off = 32; off; off >>= 1) s += __shfl_down(s, off);
        if (lane == 0) redq[w] = s;
        __syncthreads();
        if (t == 0) {
            float tot = 0.f;
#pragma unroll
            for (int j = 0; j < 8; ++j) tot += redq[j];
            atomicAdd(Z2, tot);
        }
    }
    const float maskv = (t < 128) ? Mask[(size_t)b * 128 + t] : 0.f;
    __syncthreads();

    // ---------- Phase D: 8 layers
    for (int l = 0; l < 8; ++l) {
        // aux[m] = sum_n xs[n] * BBsum[n,m]  (BBsum from registers)
        float p0 = 0.f, p1 = 0.f;
#pragma unroll
        for (int i = 0; i < 16; ++i) {
            float xv = xs[w * 16 + i];
            p0 = fmaf(BBreg[i], xv, p0);
            p1 = fmaf(BBreg[16 + i], xv, p1);
        }
        part[w][lane] = p0;
        part[w][64 + lane] = p1;
        __syncthreads();
        float outv = 0.f;
        if (t < 128) {
            float aux = part[0][t] + part[1][t] + part[2][t] + part[3][t]
                      + part[4][t] + part[5][t] + part[6][t] + part[7][t]
                      - Bz_lds[t];
            outv = fmaf(aux, w1[l * 128 + t], b1[l * 128 + t]) +
                   fmaf(xs[t], w2[l * 128 + t], b2[l * 128 + t]);
            atomicAdd(&ssum[l * 128 + t], outv);
            atomicAdd(&ssq[l * 128 + t], outv * outv);
        }
        grid.sync();
        if (t < 128) {
            float mu  = ssum[l * 128 + t] * (1.0f / 256.0f);
            float var = ssq[l * 128 + t] * (1.0f / 256.0f) - mu * mu;
            float inv = rsqrtf(var + 1e-5f);
            float v = (outv - mu) * inv * gamma[l * 128 + t] + beta[l * 128 + t];
            v *= maskv;
            // _piecewise_clip(v) == clamp(2v, -1, 1)
            xs[t] = fminf(1.0f, fmaxf(-1.0f, 2.0f * v));
        }
        __syncthreads();
        // quad = x^T G x from register tiles; lin = x . c
        float xc0 = xs[wc0 * 32 + l31];
        float xc1 = xs[wc1 * 32 + l31];
        float s0 = 0.f, s1 = 0.f;
#pragma unroll
        for (int r = 0; r < 16; ++r) {
            float xr = xs[wr * 32 + (r & 3) + 8 * (r >> 2) + 4 * kg];
            s0 = fmaf(acc0[r], xr, s0);
            s1 = fmaf(acc1[r], xr, s1);
        }
        float vq = xc0 * s0 + xc1 * s1;
        float vl = (t < 128) ? xs[t] * c_lds[t] : 0.f;
#pragma unroll
        for (int off = 32; off; off >>= 1) {
            vq += __shfl_down(vq, off);
            vl += __shfl_down(vl, off);
        }
        if (lane == 0) { redq[w] = vq; redl[w] = vl; }
        __syncthreads();
        if (t == 0) {
            float q = 0.f, L = 0.f;
#pragma unroll
            for (int j = 0; j < 8; ++j) { q += redq[j]; L += redl[j]; }
            atomicAdd(&quad[l], q);
            atomicAdd(&lin[l], L);
        }
    }

    // x_est out (final layer only)
    if (t < 128) dout[(size_t)b * 128 + t] = xs[t];
    grid.sync();
    if (b == 0 && t < 8) {
        const float logs[8] = {0.0f,
                               0.6931471805599453f,
                               1.0986122886681098f,
                               1.3862943611198906f,
                               1.6094379124341003f,
                               1.7917594692280550f,
                               1.9459101490553132f,
                               2.0794415416798357f};
        float dis = (Z2[0] - 2.0f * lin[t] + quad[t]) * (1.0f / 32768.0f);
        dout[32768 + t] = logs[t] * dis;
    }
}

extern "C" void kernel_launch(void* const* d_in, const int* in_sizes, int n_in,
                              void* d_out, int out_size, void* d_ws, size_t ws_size,
                              hipStream_t stream) {
    (void)in_sizes; (void)n_in; (void)out_size; (void)ws_size;
    const float* BB    = (const float*)d_in[0];
    const float* zB    = (const float*)d_in[1];
    // d_in[2] = x : unused (x_est starts at zeros)
    const float* z     = (const float*)d_in[3];
    const float* Bmat  = (const float*)d_in[4];
    const float* Mask  = (const float*)d_in[5];
    const float* w1    = (const float*)d_in[6];
    const float* b1    = (const float*)d_in[7];
    const float* w2    = (const float*)d_in[8];
    const float* b2    = (const float*)d_in[9];
    const float* gamma = (const float*)d_in[10];
    const float* beta  = (const float*)d_in[11];

    float* ws   = (float*)d_ws;
    float* dout = (float*)d_out;
    float* ssum = ws;
    float* ssq  = ws + 1024;
    float* quad = ws + 2048;
    float* lin  = ws + 2056;
    float* Z2   = ws + 2064;

    zero_kernel<<<(ZERO_COUNT + 255) / 256, 256, 0, stream>>>(ws, ZERO_COUNT);

    void* args[] = {(void*)&BB, (void*)&zB, (void*)&z, (void*)&Bmat, (void*)&Mask,
                    (void*)&w1, (void*)&b1, (void*)&w2, (void*)&b2,
                    (void*)&gamma, (void*)&beta,
                    (void*)&ssum, (void*)&ssq, (void*)&quad, (void*)&lin,
                    (void*)&Z2, (void*)&dout};
    hipLaunchCooperativeKernel((void*)scnet_fused, dim3(256), dim3(512), args, 0, stream);
}

// Round 4
// 716.470 us; speedup vs baseline: 1.2704x; 1.2704x over previous
//
#include <hip/hip_runtime.h>
#include <hip/hip_cooperative_groups.h>

namespace cg = cooperative_groups;

typedef __attribute__((ext_vector_type(8))) short bf16x8;
typedef __attribute__((ext_vector_type(16))) float f32x16;

#define KC 64
#define LDST 72
#define GRAM_BLOCKS 512
#define RED_BLOCKS 1024

// ---------------- workspace layout (floats) ----------------
constexpr size_t OFF_G0   = 0;          // 4194304
constexpr size_t OFF_G1   = 4194304;    // 4194304
constexpr size_t OFF_BBS  = 8388608;    // 4194304
constexpr size_t OFF_C0   = 12582912;   // 32768
constexpr size_t OFF_C1   = 12615680;   // 32768
constexpr size_t OFF_SSUM = 12648448;   // 1024
constexpr size_t OFF_SSQ  = 12649472;   // 1024
constexpr size_t OFF_QUAD = 12650496;   // 8
constexpr size_t OFF_LIN  = 12650504;   // 8
constexpr size_t OFF_Z2   = 12650512;   // 1
constexpr int ZERO_COUNT  = 1024 + 1024 + 8 + 8 + 1;  // 2065 (ssum..Z2)

__device__ inline ushort f2bf(float f) {
    unsigned u = __float_as_uint(f);
    return (ushort)((u + 0x7FFFu + ((u >> 16) & 1u)) >> 16);
}

__global__ __launch_bounds__(256) void zero_kernel(float* __restrict__ p, int n) {
    int i = blockIdx.x * 256 + threadIdx.x;
    if (i < n) p[i] = 0.0f;
}

// ---------------- mega: concurrent Gram (K-split) + BB k-reduce ----------
// blocks [0, 512): gram for batch b = bid/2, K-half = bid&1 (2048 cols, 32 chunks).
//   Writes partial G into G0/G1 and c into c0/c1 (non-atomic).
// blocks [512, 1536): BBsum reduce, coalesced shuffle form, 4096 outputs/block.
__global__ __launch_bounds__(512, 4) void mega_kernel(
    const float* __restrict__ Bmat, const float* __restrict__ z,
    const float* __restrict__ BB,
    float* __restrict__ G0, float* __restrict__ G1,
    float* __restrict__ c0, float* __restrict__ c1,
    float* __restrict__ BBsum)
{
    const int bid = blockIdx.x;
    const int t = threadIdx.x;

    __shared__ ushort As[2][128 * LDST];   // 36 KiB
    __shared__ ushort zsb[2][64];

    if (bid < GRAM_BLOCKS) {
        const int b = bid >> 1, half = bid & 1;
        const int w = t >> 6, lane = t & 63;
        const int l31 = lane & 31, kg = lane >> 5;
        const int wr = w >> 1, wc0 = (w & 1) * 2, wc1 = wc0 + 1;
        const bool dg = (wr == wc0) || (wr == wc1);

        const float* Bb = Bmat + (size_t)b * 524288 + half * 2048;
        const float* zb = z + (size_t)b * 4096 + half * 2048;

        f32x16 acc0, acc1, cacc;
#pragma unroll
        for (int i = 0; i < 16; ++i) { acc0[i] = 0.f; acc1[i] = 0.f; cacc[i] = 0.f; }

        const int foff_a  = (wr  * 32 + l31) * LDST + kg * 8;
        const int foff_b0 = (wc0 * 32 + l31) * LDST + kg * 8;
        const int foff_b1 = (wc1 * 32 + l31) * LDST + kg * 8;

        float4 pre[4];
#pragma unroll
        for (int i = 0; i < 4; ++i) {
            int f = t + 512 * i;
            int r = f >> 4, c4 = f & 15;
            pre[i] = *(const float4*)(Bb + (size_t)r * 4096 + c4 * 4);
        }
        float4 zpre;
        if (t < 16) zpre = *(const float4*)(zb + t * 4);

        for (int ch = 0; ch < 32; ++ch) {
            const int cur = ch & 1;
#pragma unroll
            for (int i = 0; i < 4; ++i) {
                int f = t + 512 * i;
                int r = f >> 4, c4 = f & 15;
                *(ushort4*)&As[cur][r * LDST + c4 * 4] =
                    make_ushort4(f2bf(pre[i].x), f2bf(pre[i].y), f2bf(pre[i].z), f2bf(pre[i].w));
            }
            if (t < 16)
                *(ushort4*)&zsb[cur][t * 4] =
                    make_ushort4(f2bf(zpre.x), f2bf(zpre.y), f2bf(zpre.z), f2bf(zpre.w));
            __syncthreads();
            if (ch < 31) {
                const float* src = Bb + (ch + 1) * KC;
#pragma unroll
                for (int i = 0; i < 4; ++i) {
                    int f = t + 512 * i;
                    int r = f >> 4, c4 = f & 15;
                    pre[i] = *(const float4*)(src + (size_t)r * 4096 + c4 * 4);
                }
                if (t < 16) zpre = *(const float4*)(zb + (ch + 1) * KC + t * 4);
            }
#pragma unroll
            for (int ks = 0; ks < 4; ++ks) {
                bf16x8 a   = *(const bf16x8*)&As[cur][foff_a + ks * 16];
                bf16x8 bf0 = *(const bf16x8*)&As[cur][foff_b0 + ks * 16];
                bf16x8 bf1 = *(const bf16x8*)&As[cur][foff_b1 + ks * 16];
                acc0 = __builtin_amdgcn_mfma_f32_32x32x16_bf16(a, bf0, acc0, 0, 0, 0);
                acc1 = __builtin_amdgcn_mfma_f32_32x32x16_bf16(a, bf1, acc1, 0, 0, 0);
                if (dg) {
                    bf16x8 zf;
#pragma unroll
                    for (int i = 0; i < 8; ++i) zf[i] = 0;
                    if (l31 == 0) zf = *(const bf16x8*)&zsb[cur][ks * 16 + kg * 8];
                    cacc = __builtin_amdgcn_mfma_f32_32x32x16_bf16(a, zf, cacc, 0, 0, 0);
                }
            }
            // double-buffered: next iter writes the other LDS half
        }

        // write partial G (non-atomic; halves combined in layers_kernel)
        float* Gp = (half ? G1 : G0) + (size_t)b * 16384;
#pragma unroll
        for (int r = 0; r < 16; ++r) {
            int row = wr * 32 + (r & 3) + 8 * (r >> 2) + 4 * kg;
            Gp[row * 128 + wc0 * 32 + l31] = acc0[r];
            Gp[row * 128 + wc1 * 32 + l31] = acc1[r];
        }
        if (dg && l31 == 0) {
            float* cp = (half ? c1 : c0) + (size_t)b * 128;
#pragma unroll
            for (int r = 0; r < 16; ++r) {
                int row = wr * 32 + (r & 3) + 8 * (r >> 2) + 4 * kg;
                cp[row] = cacc[r];
            }
        }
    } else {
        // ---- BBsum reduce: coalesced, shuffle-combined ----
        const int rb = bid - GRAM_BLOCKS;
        const size_t out_base = (size_t)rb * 4096;          // 4096 outputs/block
        const float4* BB4 = (const float4*)BB;
#pragma unroll 4
        for (int it = 0; it < 64; ++it) {
            size_t ff = out_base * 8 + (size_t)it * 512 + t; // float4 index
            float4 v = BB4[ff];
            float s = v.x + v.y + v.z + v.w;
            s += __shfl_xor(s, 1);
            s += __shfl_xor(s, 2);
            s += __shfl_xor(s, 4);
            if ((t & 7) == 0)
                BBsum[out_base + it * 64 + (t >> 3)] = s;
        }
    }
}

// ---------------- cooperative layer chain ----------------
// 256 blocks x 512 threads, one block per batch element. 9 grid.syncs total.
__global__ __launch_bounds__(512) void layers_kernel(
    const float* __restrict__ zB, const float* __restrict__ z,
    const float* __restrict__ Mask,
    const float* __restrict__ w1, const float* __restrict__ b1,
    const float* __restrict__ w2, const float* __restrict__ b2,
    const float* __restrict__ gamma, const float* __restrict__ beta,
    const float* __restrict__ BBsum,
    const float* __restrict__ G0, const float* __restrict__ G1,
    const float* __restrict__ c0, const float* __restrict__ c1,
    float* __restrict__ ssum, float* __restrict__ ssq,
    float* __restrict__ quad, float* __restrict__ lin,
    float* __restrict__ Z2, float* __restrict__ dout)
{
    cg::grid_group grid = cg::this_grid();
    const int b = blockIdx.x;
    const int t = threadIdx.x;
    const int w = t >> 6, lane = t & 63;
    const int g = t >> 7, m = t & 127;

    __shared__ float xs[128];
    __shared__ float part[4][128];
    __shared__ float Bz[128];
    __shared__ float cl[128];
    __shared__ float red1[8], red2[8];

    // phase 0: Bz reduce, c combine, z^2, x_est = 0
    if (t < 128) {
        const float4* p = (const float4*)(zB + (size_t)b * 4096 + (size_t)t * 32);
        float s = 0.f;
#pragma unroll
        for (int j = 0; j < 8; ++j) { float4 v = p[j]; s += v.x + v.y + v.z + v.w; }
        Bz[t] = s;
        cl[t] = c0[(size_t)b * 128 + t] + c1[(size_t)b * 128 + t];
        xs[t] = 0.f;
    }
    const float maskv = (t < 128) ? Mask[(size_t)b * 128 + t] : 0.f;
    {
        const float4* z4 = (const float4*)(z + (size_t)b * 4096);
        float4 a0 = z4[t * 2], a1 = z4[t * 2 + 1];
        float s = a0.x * a0.x + a0.y * a0.y + a0.z * a0.z + a0.w * a0.w
                + a1.x * a1.x + a1.y * a1.y + a1.z * a1.z + a1.w * a1.w;
#pragma unroll
        for (int off = 32; off; off >>= 1) s += __shfl_down(s, off);
        if (lane == 0) red1[w] = s;
        __syncthreads();
        if (t == 0) {
            float tot = 0.f;
#pragma unroll
            for (int j = 0; j < 8; ++j) tot += red1[j];
            atomicAdd(Z2, tot);
        }
    }
    __syncthreads();

    const float* BBb = BBsum + (size_t)b * 16384;
    const float* g0  = G0 + (size_t)b * 16384;
    const float* g1  = G1 + (size_t)b * 16384;

    for (int l = 0; l < 8; ++l) {
        // aux matvec: 4 groups x 32 n's
        float p = 0.f;
#pragma unroll 8
        for (int n = g * 32; n < g * 32 + 32; ++n)
            p = fmaf(xs[n], BBb[n * 128 + m], p);
        part[g][m] = p;
        __syncthreads();
        float outv = 0.f;
        if (t < 128) {
            float aux = part[0][t] + part[1][t] + part[2][t] + part[3][t] - Bz[t];
            outv = fmaf(aux, w1[l * 128 + t], b1[l * 128 + t]) +
                   fmaf(xs[t], w2[l * 128 + t], b2[l * 128 + t]);
            atomicAdd(&ssum[l * 128 + t], outv);
            atomicAdd(&ssq[l * 128 + t], outv * outv);
        }
        grid.sync();
        if (t < 128) {
            float mu  = ssum[l * 128 + t] * (1.0f / 256.0f);
            float var = ssq[l * 128 + t] * (1.0f / 256.0f) - mu * mu;
            float inv = rsqrtf(var + 1e-5f);
            float v = (outv - mu) * inv * gamma[l * 128 + t] + beta[l * 128 + t];
            v *= maskv;
            xs[t] = fminf(1.0f, fmaxf(-1.0f, 2.0f * v));  // piecewise_clip == clamp(2v)
        }
        __syncthreads();
        // quad matvec with G = G0 + G1
        float q = 0.f;
#pragma unroll 8
        for (int n = g * 32; n < g * 32 + 32; ++n)
            q = fmaf(xs[n], g0[n * 128 + m] + g1[n * 128 + m], q);
        part[g][m] = q;
        __syncthreads();
        float vq = 0.f, vl = 0.f;
        if (t < 128) {
            float sm = part[0][t] + part[1][t] + part[2][t] + part[3][t];
            vq = xs[t] * sm;
            vl = xs[t] * cl[t];
        }
#pragma unroll
        for (int off = 32; off; off >>= 1) {
            vq += __shfl_down(vq, off);
            vl += __shfl_down(vl, off);
        }
        if (lane == 0) { red1[w] = vq; red2[w] = vl; }
        __syncthreads();
        if (t == 0) {
            float qq = 0.f, LL = 0.f;
#pragma unroll
            for (int j = 0; j < 8; ++j) { qq += red1[j]; LL += red2[j]; }
            atomicAdd(&quad[l], qq);
            atomicAdd(&lin[l], LL);
        }
        __syncthreads();
    }

    if (t < 128) dout[(size_t)b * 128 + t] = xs[t];
    grid.sync();
    if (b == 0 && t < 8) {
        const float logs[8] = {0.0f,
                               0.6931471805599453f,
                               1.0986122886681098f,
                               1.3862943611198906f,
                               1.6094379124341003f,
                               1.7917594692280550f,
                               1.9459101490553132f,
                               2.0794415416798357f};
        float dis = (Z2[0] - 2.0f * lin[t] + quad[t]) * (1.0f / 32768.0f);
        dout[32768 + t] = logs[t] * dis;
    }
}

extern "C" void kernel_launch(void* const* d_in, const int* in_sizes, int n_in,
                              void* d_out, int out_size, void* d_ws, size_t ws_size,
                              hipStream_t stream) {
    (void)in_sizes; (void)n_in; (void)out_size; (void)ws_size;
    const float* BB    = (const float*)d_in[0];
    const float* zB    = (const float*)d_in[1];
    // d_in[2] = x : unused (x_est starts at zeros)
    const float* z     = (const float*)d_in[3];
    const float* Bmat  = (const float*)d_in[4];
    const float* Mask  = (const float*)d_in[5];
    const float* w1    = (const float*)d_in[6];
    const float* b1    = (const float*)d_in[7];
    const float* w2    = (const float*)d_in[8];
    const float* b2    = (const float*)d_in[9];
    const float* gamma = (const float*)d_in[10];
    const float* beta  = (const float*)d_in[11];

    float* ws   = (float*)d_ws;
    float* dout = (float*)d_out;
    float* G0    = ws + OFF_G0;
    float* G1    = ws + OFF_G1;
    float* BBsum = ws + OFF_BBS;
    float* c0    = ws + OFF_C0;
    float* c1    = ws + OFF_C1;
    float* ssum  = ws + OFF_SSUM;
    float* ssq   = ws + OFF_SSQ;
    float* quad  = ws + OFF_QUAD;
    float* lin   = ws + OFF_LIN;
    float* Z2    = ws + OFF_Z2;

    zero_kernel<<<(ZERO_COUNT + 255) / 256, 256, 0, stream>>>(ws + OFF_SSUM, ZERO_COUNT);
    mega_kernel<<<GRAM_BLOCKS + RED_BLOCKS, 512, 0, stream>>>(Bmat, z, BB, G0, G1, c0, c1, BBsum);

    void* args[] = {(void*)&zB, (void*)&z, (void*)&Mask,
                    (void*)&w1, (void*)&b1, (void*)&w2, (void*)&b2,
                    (void*)&gamma, (void*)&beta,
                    (void*)&BBsum, (void*)&G0, (void*)&G1, (void*)&c0, (void*)&c1,
                    (void*)&ssum, (void*)&ssq, (void*)&quad, (void*)&lin,
                    (void*)&Z2, (void*)&dout};
    hipLaunchCooperativeKernel((void*)layers_kernel, dim3(256), dim3(512), args, 0, stream);
}

// Round 5
// 570.698 us; speedup vs baseline: 1.5949x; 1.2554x over previous
//
#include <hip/hip_runtime.h>
#include <hip/hip_cooperative_groups.h>

namespace cg = cooperative_groups;

typedef __attribute__((ext_vector_type(8))) short bf16x8;
typedef __attribute__((ext_vector_type(16))) float f32x16;

#define KC 64
#define LDST 72

// ---------------- workspace layout (floats) ----------------
constexpr size_t OFF_G0   = 0;          // 4194304
constexpr size_t OFF_G1   = 4194304;    // 4194304
constexpr size_t OFF_BBS  = 8388608;    // 4194304
constexpr size_t OFF_C0   = 12582912;   // 32768
constexpr size_t OFF_C1   = 12615680;   // 32768
constexpr size_t OFF_SSUM = 12648448;   // 1024
constexpr size_t OFF_SSQ  = 12649472;   // 1024
constexpr size_t OFF_QUAD = 12650496;   // 8
constexpr size_t OFF_LIN  = 12650504;   // 8
constexpr size_t OFF_Z2   = 12650512;   // 1
constexpr int ZERO_COUNT  = 1024 + 1024 + 8 + 8 + 1;  // 2065

__device__ inline ushort f2bf(float f) {
    unsigned u = __float_as_uint(f);
    return (ushort)((u + 0x7FFFu + ((u >> 16) & 1u)) >> 16);
}

__global__ __launch_bounds__(256) void zero_kernel(float* __restrict__ p, int n) {
    int i = blockIdx.x * 256 + threadIdx.x;
    if (i < n) p[i] = 0.0f;
}

// ---------------- mega: paired gram + BB-reduce per block ----------------
// 512 blocks x 512 thr, 2 blocks/CU. Block i:
//   (1) gram for batch b=i>>1, K-half=i&1 (2048 cols, 32 chunks) -> G0/G1, c0/c1
//   (2) BBsum reduce for outputs [i*8192, (i+1)*8192)  (1 MB of BB)
// Homogeneous blocks -> perfect balance, reduce loads overlap gram MFMA tails.
__global__ __launch_bounds__(512, 4) void mega_kernel(
    const float* __restrict__ Bmat, const float* __restrict__ z,
    const float* __restrict__ BB,
    float* __restrict__ G0, float* __restrict__ G1,
    float* __restrict__ c0, float* __restrict__ c1,
    float* __restrict__ BBsum)
{
    const int bid = blockIdx.x;
    const int t = threadIdx.x;

    __shared__ ushort As[2][128 * LDST];   // 36 KiB
    __shared__ ushort zsb[2][64];

    // ======== phase 1: gram ========
    {
        const int b = bid >> 1, half = bid & 1;
        const int w = t >> 6, lane = t & 63;
        const int l31 = lane & 31, kg = lane >> 5;
        const int wr = w >> 1, wc0 = (w & 1) * 2, wc1 = wc0 + 1;
        const bool dg = (wr == wc0) || (wr == wc1);

        const float* Bb = Bmat + (size_t)b * 524288 + half * 2048;
        const float* zb = z + (size_t)b * 4096 + half * 2048;

        f32x16 acc0, acc1, cacc;
#pragma unroll
        for (int i = 0; i < 16; ++i) { acc0[i] = 0.f; acc1[i] = 0.f; cacc[i] = 0.f; }

        const int foff_a  = (wr  * 32 + l31) * LDST + kg * 8;
        const int foff_b0 = (wc0 * 32 + l31) * LDST + kg * 8;
        const int foff_b1 = (wc1 * 32 + l31) * LDST + kg * 8;

        float4 pre[4];
#pragma unroll
        for (int i = 0; i < 4; ++i) {
            int f = t + 512 * i;
            int r = f >> 4, c4 = f & 15;
            pre[i] = *(const float4*)(Bb + (size_t)r * 4096 + c4 * 4);
        }
        float4 zpre;
        if (t < 16) zpre = *(const float4*)(zb + t * 4);

        for (int ch = 0; ch < 32; ++ch) {
            const int cur = ch & 1;
#pragma unroll
            for (int i = 0; i < 4; ++i) {
                int f = t + 512 * i;
                int r = f >> 4, c4 = f & 15;
                *(ushort4*)&As[cur][r * LDST + c4 * 4] =
                    make_ushort4(f2bf(pre[i].x), f2bf(pre[i].y), f2bf(pre[i].z), f2bf(pre[i].w));
            }
            if (t < 16)
                *(ushort4*)&zsb[cur][t * 4] =
                    make_ushort4(f2bf(zpre.x), f2bf(zpre.y), f2bf(zpre.z), f2bf(zpre.w));
            __syncthreads();
            if (ch < 31) {
                const float* src = Bb + (ch + 1) * KC;
#pragma unroll
                for (int i = 0; i < 4; ++i) {
                    int f = t + 512 * i;
                    int r = f >> 4, c4 = f & 15;
                    pre[i] = *(const float4*)(src + (size_t)r * 4096 + c4 * 4);
                }
                if (t < 16) zpre = *(const float4*)(zb + (ch + 1) * KC + t * 4);
            }
#pragma unroll
            for (int ks = 0; ks < 4; ++ks) {
                bf16x8 a   = *(const bf16x8*)&As[cur][foff_a + ks * 16];
                bf16x8 bf0 = *(const bf16x8*)&As[cur][foff_b0 + ks * 16];
                bf16x8 bf1 = *(const bf16x8*)&As[cur][foff_b1 + ks * 16];
                acc0 = __builtin_amdgcn_mfma_f32_32x32x16_bf16(a, bf0, acc0, 0, 0, 0);
                acc1 = __builtin_amdgcn_mfma_f32_32x32x16_bf16(a, bf1, acc1, 0, 0, 0);
                if (dg) {
                    bf16x8 zf;
#pragma unroll
                    for (int i = 0; i < 8; ++i) zf[i] = 0;
                    if (l31 == 0) zf = *(const bf16x8*)&zsb[cur][ks * 16 + kg * 8];
                    cacc = __builtin_amdgcn_mfma_f32_32x32x16_bf16(a, zf, cacc, 0, 0, 0);
                }
            }
        }

        float* Gp = (half ? G1 : G0) + (size_t)b * 16384;
#pragma unroll
        for (int r = 0; r < 16; ++r) {
            int row = wr * 32 + (r & 3) + 8 * (r >> 2) + 4 * kg;
            Gp[row * 128 + wc0 * 32 + l31] = acc0[r];
            Gp[row * 128 + wc1 * 32 + l31] = acc1[r];
        }
        if (dg && l31 == 0) {
            float* cp = (half ? c1 : c0) + (size_t)b * 128;
#pragma unroll
            for (int r = 0; r < 16; ++r) {
                int row = wr * 32 + (r & 3) + 8 * (r >> 2) + 4 * kg;
                cp[row] = cacc[r];
            }
        }
    }

    // ======== phase 2: BBsum reduce (register-only, no sync needed) ========
    {
        const size_t out_base = (size_t)bid * 8192;
#pragma unroll 2
        for (int i = 0; i < 16; ++i) {
            size_t o = out_base + (size_t)i * 512 + t;
            const float4* p = (const float4*)(BB + o * 32);
            float s = 0.f;
#pragma unroll
            for (int j = 0; j < 8; ++j) { float4 v = p[j]; s += v.x + v.y + v.z + v.w; }
            BBsum[o] = s;
        }
    }
}

// ---------------- cooperative layer chain, LDS-resident matrices ----------
// 256 blocks x 1024 thr (1 block/CU). Phase 0: G = G0+G1 and BBsum -> LDS.
// 8 layers: LDS matvecs + 1 grid.sync each for BN batch stats.
__global__ __launch_bounds__(1024) void layers_kernel(
    const float* __restrict__ zB, const float* __restrict__ z,
    const float* __restrict__ Mask,
    const float* __restrict__ w1, const float* __restrict__ b1,
    const float* __restrict__ w2, const float* __restrict__ b2,
    const float* __restrict__ gamma, const float* __restrict__ beta,
    const float* __restrict__ BBsum,
    const float* __restrict__ G0, const float* __restrict__ G1,
    const float* __restrict__ c0, const float* __restrict__ c1,
    float* __restrict__ ssum, float* __restrict__ ssq,
    float* __restrict__ quad, float* __restrict__ lin,
    float* __restrict__ Z2, float* __restrict__ dout)
{
    cg::grid_group grid = cg::this_grid();
    const int b = blockIdx.x;
    const int t = threadIdx.x;
    const int w = t >> 6, lane = t & 63;
    const int m4 = t & 31, g = t >> 5;     // matvec roles: f4-col, n-group

    __shared__ float Gs[16384];            // 64 KiB
    __shared__ float Bs[16384];            // 64 KiB
    __shared__ float4 part[32][33];        // 16.9 KiB (pad 33 vs bank alias)
    __shared__ float xs[128];
    __shared__ float Bz[128];
    __shared__ float cl[128];
    __shared__ float red1[16], red2[16];

    // ---- phase 0: stage LDS, Bz, c, z^2, x_est=0
    {
        const float4* g04 = (const float4*)(G0 + (size_t)b * 16384);
        const float4* g14 = (const float4*)(G1 + (size_t)b * 16384);
        const float4* bb4 = (const float4*)(BBsum + (size_t)b * 16384);
        float4* Gs4 = (float4*)Gs;
        float4* Bs4 = (float4*)Bs;
#pragma unroll
        for (int i = 0; i < 4; ++i) {
            int idx = i * 1024 + t;
            float4 a = g04[idx], bq = g14[idx];
            Gs4[idx] = make_float4(a.x + bq.x, a.y + bq.y, a.z + bq.z, a.w + bq.w);
            Bs4[idx] = bb4[idx];
        }
        if (t < 128) {
            const float4* p = (const float4*)(zB + (size_t)b * 4096 + (size_t)t * 32);
            float s = 0.f;
#pragma unroll
            for (int j = 0; j < 8; ++j) { float4 v = p[j]; s += v.x + v.y + v.z + v.w; }
            Bz[t] = s;
            cl[t] = c0[(size_t)b * 128 + t] + c1[(size_t)b * 128 + t];
            xs[t] = 0.f;
        }
        // z^2 partial
        float4 v = ((const float4*)(z + (size_t)b * 4096))[t];
        float s = v.x * v.x + v.y * v.y + v.z * v.z + v.w * v.w;
#pragma unroll
        for (int off = 32; off; off >>= 1) s += __shfl_down(s, off);
        if (lane == 0) red1[w] = s;
        __syncthreads();
        if (t == 0) {
            float tot = 0.f;
#pragma unroll
            for (int j = 0; j < 16; ++j) tot += red1[j];
            atomicAdd(Z2, tot);
        }
    }
    const float maskv = (t < 128) ? Mask[(size_t)b * 128 + t] : 0.f;
    __syncthreads();

    const float* partf = (const float*)part;

    for (int l = 0; l < 8; ++l) {
        // ---- aux matvec from LDS Bs with current xs
        {
            float4 acc = make_float4(0.f, 0.f, 0.f, 0.f);
            const float4* Bs4 = (const float4*)Bs;
#pragma unroll
            for (int i = 0; i < 4; ++i) {
                int n = g * 4 + i;
                float xv = xs[n];
                float4 mv = Bs4[n * 32 + m4];
                acc.x = fmaf(xv, mv.x, acc.x);
                acc.y = fmaf(xv, mv.y, acc.y);
                acc.z = fmaf(xv, mv.z, acc.z);
                acc.w = fmaf(xv, mv.w, acc.w);
            }
            part[g][m4] = acc;
        }
        __syncthreads();
        float outv = 0.f;
        if (t < 128) {
            float aux = -Bz[t];
            const int base = (t >> 2) * 4 + (t & 3);   // part[g][m>>2][m&3]
#pragma unroll
            for (int g2 = 0; g2 < 32; ++g2)
                aux += partf[g2 * 132 + base];
            outv = fmaf(aux, w1[l * 128 + t], b1[l * 128 + t]) +
                   fmaf(xs[t], w2[l * 128 + t], b2[l * 128 + t]);
            atomicAdd(&ssum[l * 128 + t], outv);
            atomicAdd(&ssq[l * 128 + t], outv * outv);
        }
        grid.sync();
        if (t < 128) {
            float mu  = ssum[l * 128 + t] * (1.0f / 256.0f);
            float var = ssq[l * 128 + t] * (1.0f / 256.0f) - mu * mu;
            float inv = rsqrtf(var + 1e-5f);
            float v = (outv - mu) * inv * gamma[l * 128 + t] + beta[l * 128 + t];
            v *= maskv;
            xs[t] = fminf(1.0f, fmaxf(-1.0f, 2.0f * v));  // piecewise_clip == clamp(2v)
        }
        __syncthreads();
        // ---- quad matvec from LDS Gs with new xs
        {
            float4 acc = make_float4(0.f, 0.f, 0.f, 0.f);
            const float4* Gs4 = (const float4*)Gs;
#pragma unroll
            for (int i = 0; i < 4; ++i) {
                int n = g * 4 + i;
                float xv = xs[n];
                float4 mv = Gs4[n * 32 + m4];
                acc.x = fmaf(xv, mv.x, acc.x);
                acc.y = fmaf(xv, mv.y, acc.y);
                acc.z = fmaf(xv, mv.z, acc.z);
                acc.w = fmaf(xv, mv.w, acc.w);
            }
            part[g][m4] = acc;
        }
        __syncthreads();
        {
            float vq = 0.f, vl = 0.f;
            if (t < 128) {
                float gx = 0.f;
                const int base = (t >> 2) * 4 + (t & 3);
#pragma unroll
                for (int g2 = 0; g2 < 32; ++g2)
                    gx += partf[g2 * 132 + base];
                vq = xs[t] * gx;
                vl = xs[t] * cl[t];
            }
#pragma unroll
            for (int off = 32; off; off >>= 1) {
                vq += __shfl_down(vq, off);
                vl += __shfl_down(vl, off);
            }
            if (t < 128 && lane == 0) { red1[w] = vq; red2[w] = vl; }
        }
        __syncthreads();
        if (t == 0) {
            atomicAdd(&quad[l], red1[0] + red1[1]);
            atomicAdd(&lin[l],  red2[0] + red2[1]);
        }
        __syncthreads();
    }

    if (t < 128) dout[(size_t)b * 128 + t] = xs[t];
    grid.sync();
    if (b == 0 && t < 8) {
        const float logs[8] = {0.0f,
                               0.6931471805599453f,
                               1.0986122886681098f,
                               1.3862943611198906f,
                               1.6094379124341003f,
                               1.7917594692280550f,
                               1.9459101490553132f,
                               2.0794415416798357f};
        float dis = (Z2[0] - 2.0f * lin[t] + quad[t]) * (1.0f / 32768.0f);
        dout[32768 + t] = logs[t] * dis;
    }
}

extern "C" void kernel_launch(void* const* d_in, const int* in_sizes, int n_in,
                              void* d_out, int out_size, void* d_ws, size_t ws_size,
                              hipStream_t stream) {
    (void)in_sizes; (void)n_in; (void)out_size; (void)ws_size;
    const float* BB    = (const float*)d_in[0];
    const float* zB    = (const float*)d_in[1];
    // d_in[2] = x : unused (x_est starts at zeros)
    const float* z     = (const float*)d_in[3];
    const float* Bmat  = (const float*)d_in[4];
    const float* Mask  = (const float*)d_in[5];
    const float* w1    = (const float*)d_in[6];
    const float* b1    = (const float*)d_in[7];
    const float* w2    = (const float*)d_in[8];
    const float* b2    = (const float*)d_in[9];
    const float* gamma = (const float*)d_in[10];
    const float* beta  = (const float*)d_in[11];

    float* ws   = (float*)d_ws;
    float* dout = (float*)d_out;
    float* G0    = ws + OFF_G0;
    float* G1    = ws + OFF_G1;
    float* BBsum = ws + OFF_BBS;
    float* c0    = ws + OFF_C0;
    float* c1    = ws + OFF_C1;
    float* ssum  = ws + OFF_SSUM;
    float* ssq   = ws + OFF_SSQ;
    float* quad  = ws + OFF_QUAD;
    float* lin   = ws + OFF_LIN;
    float* Z2    = ws + OFF_Z2;

    zero_kernel<<<(ZERO_COUNT + 255) / 256, 256, 0, stream>>>(ws + OFF_SSUM, ZERO_COUNT);
    mega_kernel<<<512, 512, 0, stream>>>(Bmat, z, BB, G0, G1, c0, c1, BBsum);

    void* args[] = {(void*)&zB, (void*)&z, (void*)&Mask,
                    (void*)&w1, (void*)&b1, (void*)&w2, (void*)&b2,
                    (void*)&gamma, (void*)&beta,
                    (void*)&BBsum, (void*)&G0, (void*)&G1, (void*)&c0, (void*)&c1,
                    (void*)&ssum, (void*)&ssq, (void*)&quad, (void*)&lin,
                    (void*)&Z2, (void*)&dout};
    hipLaunchCooperativeKernel((void*)layers_kernel, dim3(256), dim3(1024), args, 0, stream);
}

// Round 7
// 523.127 us; speedup vs baseline: 1.7400x; 1.0909x over previous
//
#include <hip/hip_runtime.h>
#include <hip/hip_cooperative_groups.h>

typedef __attribute__((ext_vector_type(8))) short bf16x8;
typedef __attribute__((ext_vector_type(16))) float f32x16;

#define KC 64
#define LDST 72

// ---------------- workspace layout (floats) ----------------
constexpr size_t OFF_G    = 0;          // 4194304
constexpr size_t OFF_BBS  = 4194304;    // 4194304
constexpr size_t OFF_C    = 8388608;    // 32768
constexpr size_t OFF_SSUM = 8421376;    // 1024
constexpr size_t OFF_SSQ  = 8422400;    // 1024
constexpr size_t OFF_QUAD = 8423424;    // 8
constexpr size_t OFF_LIN  = 8423432;    // 8
constexpr size_t OFF_Z2   = 8423440;    // 1
constexpr size_t OFF_CNT  = 8423444;    // 1 int
// zero from OFF_SSUM through past OFF_CNT (inclusive), with slack:
constexpr int ZERO_COUNT  = (int)(OFF_CNT - OFF_SSUM) + 8;   // 2076

__device__ inline ushort f2bf(float f) {
    unsigned u = __float_as_uint(f);
    return (ushort)((u + 0x7FFFu + ((u >> 16) & 1u)) >> 16);
}

__global__ __launch_bounds__(256) void zero_kernel(float* __restrict__ p, int n) {
    int i = blockIdx.x * 256 + threadIdx.x;
    if (i < n) p[i] = 0.0f;
}

// ---------------- BBsum[b,n,m] = sum_k BB[b,n,m,k] (pure stream) -----------
__global__ __launch_bounds__(256) void reduce_bb(const float* __restrict__ BB,
                                                 float* __restrict__ BBsum) {
    size_t o = (size_t)blockIdx.x * 256 + threadIdx.x;   // 4,194,304 outputs
    const float4* p = reinterpret_cast<const float4*>(BB + o * 32);
    float s = 0.f;
#pragma unroll
    for (int i = 0; i < 8; ++i) {
        float4 v = p[i];
        s += v.x + v.y + v.z + v.w;
    }
    BBsum[o] = s;
}

// ---------------- Gram via MFMA (R2-proven shape): G_b = B_b B_b^T, c_b = B_b z_b
// One block (1024 thr = 16 waves) per batch. Wave w owns tile (w>>2, w&3).
__global__ __launch_bounds__(1024) void gram_mfma(const float* __restrict__ Bmat,
                                                  const float* __restrict__ z,
                                                  float* __restrict__ G,
                                                  float* __restrict__ cvec) {
    const int b = blockIdx.x;
    const int t = threadIdx.x;
    const int w = t >> 6;
    const int lane = t & 63;
    const int wr = w >> 2, wc = w & 3;
    const bool diag = (wr == wc);
    const int kg = lane >> 5;
    const int l31 = lane & 31;

    const float* Bb = Bmat + (size_t)b * (128 * 4096);
    const float* zb = z + (size_t)b * 4096;

    __shared__ ushort As[2][128 * LDST];
    __shared__ ushort zsb[2][64];

    const int c4 = t & 15;
    const int r0 = t >> 4;

    f32x16 acc, cacc;
#pragma unroll
    for (int i = 0; i < 16; ++i) { acc[i] = 0.f; cacc[i] = 0.f; }

    const int foff_a = (wr * 32 + l31) * LDST + kg * 8;
    const int foff_b = (wc * 32 + l31) * LDST + kg * 8;

    float4 pre0 = *(const float4*)(Bb + (size_t)r0 * 4096 + c4 * 4);
    float4 pre1 = *(const float4*)(Bb + (size_t)(r0 + 64) * 4096 + c4 * 4);
    float4 zpre;
    if (t < 16) zpre = *(const float4*)(zb + t * 4);

    for (int ch = 0; ch < 64; ++ch) {
        const int cur = ch & 1;
        {
            *(ushort4*)&As[cur][r0 * LDST + c4 * 4] =
                make_ushort4(f2bf(pre0.x), f2bf(pre0.y), f2bf(pre0.z), f2bf(pre0.w));
            *(ushort4*)&As[cur][(r0 + 64) * LDST + c4 * 4] =
                make_ushort4(f2bf(pre1.x), f2bf(pre1.y), f2bf(pre1.z), f2bf(pre1.w));
            if (t < 16)
                *(ushort4*)&zsb[cur][t * 4] =
                    make_ushort4(f2bf(zpre.x), f2bf(zpre.y), f2bf(zpre.z), f2bf(zpre.w));
        }
        __syncthreads();
        if (ch < 63) {
            const float* src = Bb + (ch + 1) * KC;
            pre0 = *(const float4*)(src + (size_t)r0 * 4096 + c4 * 4);
            pre1 = *(const float4*)(src + (size_t)(r0 + 64) * 4096 + c4 * 4);
            if (t < 16) zpre = *(const float4*)(zb + (ch + 1) * KC + t * 4);
        }
#pragma unroll
        for (int ks = 0; ks < 4; ++ks) {
            bf16x8 a   = *(const bf16x8*)&As[cur][foff_a + ks * 16];
            bf16x8 bfr = *(const bf16x8*)&As[cur][foff_b + ks * 16];
            acc = __builtin_amdgcn_mfma_f32_32x32x16_bf16(a, bfr, acc, 0, 0, 0);
            if (diag) {
                bf16x8 zf;
#pragma unroll
                for (int i = 0; i < 8; ++i) zf[i] = 0;
                if (l31 == 0) zf = *(const bf16x8*)&zsb[cur][ks * 16 + kg * 8];
                cacc = __builtin_amdgcn_mfma_f32_32x32x16_bf16(a, zf, cacc, 0, 0, 0);
            }
        }
    }

    float* Gb = G + (size_t)b * 16384;
#pragma unroll
    for (int r = 0; r < 16; ++r) {
        int row = wr * 32 + (r & 3) + 8 * (r >> 2) + 4 * kg;
        Gb[row * 128 + wc * 32 + l31] = acc[r];
    }
    if (diag && l31 == 0) {
#pragma unroll
        for (int r = 0; r < 16; ++r) {
            int row = wr * 32 + (r & 3) + 8 * (r >> 2) + 4 * kg;
            cvec[b * 128 + row] = cacc[r];
        }
    }
}

// ---------------- lightweight grid barrier (no L2 flush) -------------------
// All cross-block data is written with device-scope atomics and read back
// with device-scope atomic loads (coherent point), so the barrier itself
// only needs counter semantics + ordering. Spin is bounded: a logic error
// degrades to a wrong answer instead of a 600 s hang.
__device__ inline void lsync(int* cnt, int target, int t) {
    __syncthreads();
    if (t == 0) {
        __threadfence();
        __hip_atomic_fetch_add(cnt, 1, __ATOMIC_RELEASE, __HIP_MEMORY_SCOPE_AGENT);
        int it = 0;
        while (__hip_atomic_load(cnt, __ATOMIC_ACQUIRE, __HIP_MEMORY_SCOPE_AGENT) < target
               && it < (1 << 21)) {
            __builtin_amdgcn_s_sleep(8);
            ++it;
        }
        __threadfence();
    }
    __syncthreads();
}

__device__ inline float aload(const float* p) {
    return __hip_atomic_load(p, __ATOMIC_RELAXED, __HIP_MEMORY_SCOPE_AGENT);
}

// ---------------- cooperative layer chain, LDS-resident matrices -----------
__global__ __launch_bounds__(1024) void layers_kernel(
    const float* __restrict__ zB, const float* __restrict__ z,
    const float* __restrict__ Mask,
    const float* __restrict__ w1, const float* __restrict__ b1,
    const float* __restrict__ w2, const float* __restrict__ b2,
    const float* __restrict__ gamma, const float* __restrict__ beta,
    const float* __restrict__ BBsum,
    const float* __restrict__ G, const float* __restrict__ cvec,
    float* __restrict__ ssum, float* __restrict__ ssq,
    float* __restrict__ quad, float* __restrict__ lin,
    float* __restrict__ Z2, int* __restrict__ cnt,
    float* __restrict__ dout)
{
    const int b = blockIdx.x;
    const int t = threadIdx.x;
    const int w = t >> 6, lane = t & 63;
    const int m4 = t & 31, g = t >> 5;

    __shared__ float Gs[16384];            // 64 KiB
    __shared__ float Bs[16384];            // 64 KiB
    __shared__ float4 part[32][33];        // 16.9 KiB
    __shared__ float xs[128];
    __shared__ float Bz[128];
    __shared__ float cl[128];
    __shared__ float red1[16], red2[16];

    // ---- phase 0: stage LDS, Bz, c, z^2, x_est=0
    {
        const float4* g4  = (const float4*)(G + (size_t)b * 16384);
        const float4* bb4 = (const float4*)(BBsum + (size_t)b * 16384);
        float4* Gs4 = (float4*)Gs;
        float4* Bs4 = (float4*)Bs;
#pragma unroll
        for (int i = 0; i < 4; ++i) {
            int idx = i * 1024 + t;
            Gs4[idx] = g4[idx];
            Bs4[idx] = bb4[idx];
        }
        if (t < 128) {
            const float4* p = (const float4*)(zB + (size_t)b * 4096 + (size_t)t * 32);
            float s = 0.f;
#pragma unroll
            for (int j = 0; j < 8; ++j) { float4 v = p[j]; s += v.x + v.y + v.z + v.w; }
            Bz[t] = s;
            cl[t] = cvec[(size_t)b * 128 + t];
            xs[t] = 0.f;
        }
        float4 v = ((const float4*)(z + (size_t)b * 4096))[t];
        float s = v.x * v.x + v.y * v.y + v.z * v.z + v.w * v.w;
#pragma unroll
        for (int off = 32; off; off >>= 1) s += __shfl_down(s, off);
        if (lane == 0) red1[w] = s;
        __syncthreads();
        if (t == 0) {
            float tot = 0.f;
#pragma unroll
            for (int j = 0; j < 16; ++j) tot += red1[j];
            atomicAdd(Z2, tot);
        }
    }
    const float maskv = (t < 128) ? Mask[(size_t)b * 128 + t] : 0.f;
    __syncthreads();

    const float* partf = (const float*)part;

    for (int l = 0; l < 8; ++l) {
        // ---- aux matvec from LDS Bs with current xs
        {
            float4 acc = make_float4(0.f, 0.f, 0.f, 0.f);
            const float4* Bs4 = (const float4*)Bs;
#pragma unroll
            for (int i = 0; i < 4; ++i) {
                int n = g * 4 + i;
                float xv = xs[n];
                float4 mv = Bs4[n * 32 + m4];
                acc.x = fmaf(xv, mv.x, acc.x);
                acc.y = fmaf(xv, mv.y, acc.y);
                acc.z = fmaf(xv, mv.z, acc.z);
                acc.w = fmaf(xv, mv.w, acc.w);
            }
            part[g][m4] = acc;
        }
        __syncthreads();
        float outv = 0.f;
        if (t < 128) {
            float aux = -Bz[t];
            const int base = (t >> 2) * 4 + (t & 3);
#pragma unroll
            for (int g2 = 0; g2 < 32; ++g2)
                aux += partf[g2 * 132 + base];
            outv = fmaf(aux, w1[l * 128 + t], b1[l * 128 + t]) +
                   fmaf(xs[t], w2[l * 128 + t], b2[l * 128 + t]);
            atomicAdd(&ssum[l * 128 + t], outv);
            atomicAdd(&ssq[l * 128 + t], outv * outv);
        }
        lsync(cnt, 256 * (l + 1), t);
        if (t < 128) {
            float mu  = aload(&ssum[l * 128 + t]) * (1.0f / 256.0f);
            float var = aload(&ssq[l * 128 + t]) * (1.0f / 256.0f) - mu * mu;
            float inv = rsqrtf(var + 1e-5f);
            float v = (outv - mu) * inv * gamma[l * 128 + t] + beta[l * 128 + t];
            v *= maskv;
            xs[t] = fminf(1.0f, fmaxf(-1.0f, 2.0f * v));  // piecewise_clip == clamp(2v)
        }
        __syncthreads();
        // ---- quad matvec from LDS Gs with new xs
        {
            float4 acc = make_float4(0.f, 0.f, 0.f, 0.f);
            const float4* Gs4 = (const float4*)Gs;
#pragma unroll
            for (int i = 0; i < 4; ++i) {
                int n = g * 4 + i;
                float xv = xs[n];
                float4 mv = Gs4[n * 32 + m4];
                acc.x = fmaf(xv, mv.x, acc.x);
                acc.y = fmaf(xv, mv.y, acc.y);
                acc.z = fmaf(xv, mv.z, acc.z);
                acc.w = fmaf(xv, mv.w, acc.w);
            }
            part[g][m4] = acc;
        }
        __syncthreads();
        {
            float vq = 0.f, vl = 0.f;
            if (t < 128) {
                float gx = 0.f;
                const int base = (t >> 2) * 4 + (t & 3);
#pragma unroll
                for (int g2 = 0; g2 < 32; ++g2)
                    gx += partf[g2 * 132 + base];
                vq = xs[t] * gx;
                vl = xs[t] * cl[t];
            }
#pragma unroll
            for (int off = 32; off; off >>= 1) {
                vq += __shfl_down(vq, off);
                vl += __shfl_down(vl, off);
            }
            if (t < 128 && lane == 0) { red1[w] = vq; red2[w] = vl; }
        }
        __syncthreads();
        if (t == 0) {
            atomicAdd(&quad[l], red1[0] + red1[1]);
            atomicAdd(&lin[l],  red2[0] + red2[1]);
        }
        __syncthreads();
    }

    if (t < 128) dout[(size_t)b * 128 + t] = xs[t];
    lsync(cnt, 256 * 9, t);
    if (b == 0 && t < 8) {
        const float logs[8] = {0.0f,
                               0.6931471805599453f,
                               1.0986122886681098f,
                               1.3862943611198906f,
                               1.6094379124341003f,
                               1.7917594692280550f,
                               1.9459101490553132f,
                               2.0794415416798357f};
        float dis = (aload(&Z2[0]) - 2.0f * aload(&lin[t]) + aload(&quad[t])) * (1.0f / 32768.0f);
        dout[32768 + t] = logs[t] * dis;
    }
}

extern "C" void kernel_launch(void* const* d_in, const int* in_sizes, int n_in,
                              void* d_out, int out_size, void* d_ws, size_t ws_size,
                              hipStream_t stream) {
    (void)in_sizes; (void)n_in; (void)out_size; (void)ws_size;
    const float* BB    = (const float*)d_in[0];
    const float* zB    = (const float*)d_in[1];
    // d_in[2] = x : unused (x_est starts at zeros)
    const float* z     = (const float*)d_in[3];
    const float* Bmat  = (const float*)d_in[4];
    const float* Mask  = (const float*)d_in[5];
    const float* w1    = (const float*)d_in[6];
    const float* b1    = (const float*)d_in[7];
    const float* w2    = (const float*)d_in[8];
    const float* b2    = (const float*)d_in[9];
    const float* gamma = (const float*)d_in[10];
    const float* beta  = (const float*)d_in[11];

    float* ws   = (float*)d_ws;
    float* dout = (float*)d_out;
    float* G     = ws + OFF_G;
    float* BBsum = ws + OFF_BBS;
    float* cvec  = ws + OFF_C;
    float* ssum  = ws + OFF_SSUM;
    float* ssq   = ws + OFF_SSQ;
    float* quad  = ws + OFF_QUAD;
    float* lin   = ws + OFF_LIN;
    float* Z2    = ws + OFF_Z2;
    int*   cnt   = (int*)(ws + OFF_CNT);

    zero_kernel<<<(ZERO_COUNT + 255) / 256, 256, 0, stream>>>(ws + OFF_SSUM, ZERO_COUNT);
    reduce_bb<<<16384, 256, 0, stream>>>(BB, BBsum);
    gram_mfma<<<256, 1024, 0, stream>>>(Bmat, z, G, cvec);

    void* args[] = {(void*)&zB, (void*)&z, (void*)&Mask,
                    (void*)&w1, (void*)&b1, (void*)&w2, (void*)&b2,
                    (void*)&gamma, (void*)&beta,
                    (void*)&BBsum, (void*)&G, (void*)&cvec,
                    (void*)&ssum, (void*)&ssq, (void*)&quad, (void*)&lin,
                    (void*)&Z2, (void*)&cnt, (void*)&dout};
    hipLaunchCooperativeKernel((void*)layers_kernel, dim3(256), dim3(1024), args, 0, stream);
}

// Round 8
// 388.269 us; speedup vs baseline: 2.3443x; 1.3473x over previous
//
#include <hip/hip_runtime.h>
#include <hip/hip_cooperative_groups.h>

typedef __attribute__((ext_vector_type(8))) short bf16x8;
typedef __attribute__((ext_vector_type(16))) float f32x16;

#define KC 256
#define NCH 16           // 4096 / KC
#define LROW 264         // shorts per LDS staging row (256 data + 8 pad)

// ---------------- workspace layout ----------------
// cnt (int) first, then float accumulators. All zeroed each launch.
constexpr size_t OFF_CNT  = 0;    // 1 int
constexpr size_t OFF_SSUM = 8;    // 1024 floats
constexpr size_t OFF_SSQ  = 1032;
constexpr size_t OFF_QUAD = 2056; // 8
constexpr size_t OFF_LIN  = 2064; // 8
constexpr size_t OFF_Z2   = 2072; // 1
constexpr int ZERO_COUNT  = 2080;

__device__ inline ushort f2bf(float f) {
    unsigned u = __float_as_uint(f);
    return (ushort)((u + 0x7FFFu + ((u >> 16) & 1u)) >> 16);
}

__global__ __launch_bounds__(256) void zero_kernel(float* __restrict__ p, int n) {
    int i = blockIdx.x * 256 + threadIdx.x;
    if (i < n) p[i] = 0.0f;
}

// Lean grid barrier: release-add + RELAXED spin (atomics are coherent-point;
// no plain cross-block data -> no cache maintenance needed). Bounded spin.
__device__ inline void lsync(int* cnt, int target, int t) {
    __syncthreads();
    if (t == 0) {
        __hip_atomic_fetch_add(cnt, 1, __ATOMIC_RELEASE, __HIP_MEMORY_SCOPE_AGENT);
        int it = 0;
        while (__hip_atomic_load(cnt, __ATOMIC_RELAXED, __HIP_MEMORY_SCOPE_AGENT) < target
               && it < (1 << 22)) {
            __builtin_amdgcn_s_sleep(2);
            ++it;
        }
    }
    __syncthreads();
}

__device__ inline float aload(const float* p) {
    return __hip_atomic_load(p, __ATOMIC_RELAXED, __HIP_MEMORY_SCOPE_AGENT);
}

// ---------------- fully fused: gram + BB reduce + 8 layers + losses --------
// 256 blocks x 1024 thr, 1 block/CU. LDS union: gram staging (132 KiB)
// is reused as Gs[64K] + Bs[64K] after the MFMA phase.
__global__ __launch_bounds__(1024) void scnet_all(
    const float* __restrict__ BB, const float* __restrict__ zB,
    const float* __restrict__ z, const float* __restrict__ Bmat,
    const float* __restrict__ Mask,
    const float* __restrict__ w1, const float* __restrict__ b1,
    const float* __restrict__ w2, const float* __restrict__ b2,
    const float* __restrict__ gamma, const float* __restrict__ beta,
    float* __restrict__ ssum, float* __restrict__ ssq,
    float* __restrict__ quad, float* __restrict__ lin,
    float* __restrict__ Z2, int* __restrict__ cnt,
    float* __restrict__ dout)
{
    const int b = blockIdx.x;
    const int t = threadIdx.x;
    const int w = t >> 6, lane = t & 63;
    const int l31 = lane & 31, kg = lane >> 5;

    __shared__ __align__(16) ushort U[2 * 128 * LROW];  // 135168 B union
    __shared__ ushort zsb[2][KC];                        // 1 KiB
    __shared__ float4 part[32][33];                      // 16.9 KiB
    __shared__ float xs[128];
    __shared__ float Bz[128];
    __shared__ float cl[128];
    __shared__ float red1[16], red2[16];

    // ======== phase 1: Gram via MFMA, KC=256 contiguous chunks ========
    // Wave w owns output tile (wr = w>>2, wc = w&3) of the 128x128 Gram.
    {
        const int wr = w >> 2, wc = w & 3;
        const bool diag = (wr == wc);
        const float* Bb = Bmat + (size_t)b * 524288;
        const float* zb = z + (size_t)b * 4096;

        f32x16 acc, cacc;
#pragma unroll
        for (int i = 0; i < 16; ++i) { acc[i] = 0.f; cacc[i] = 0.f; }

        const int foff_a = (wr * 32 + l31) * LROW + kg * 8;
        const int foff_b = (wc * 32 + l31) * LROW + kg * 8;

        // prefetch chunk 0: f = i*1024 + t; row r = f>>6 (wave = one row), c4 = f&63
        float4 pre[8];
#pragma unroll
        for (int i = 0; i < 8; ++i) {
            int f = i * 1024 + t;
            int r = f >> 6, c4 = f & 63;
            pre[i] = *(const float4*)(Bb + (size_t)r * 4096 + c4 * 4);
        }
        float4 zpre;
        if (t < 64) zpre = *(const float4*)(zb + t * 4);

        for (int ch = 0; ch < NCH; ++ch) {
            const int cur = ch & 1;
            ushort* As = U + cur * (128 * LROW);
#pragma unroll
            for (int i = 0; i < 8; ++i) {
                int f = i * 1024 + t;
                int r = f >> 6, c4 = f & 63;
                *(ushort4*)&As[r * LROW + c4 * 4] =
                    make_ushort4(f2bf(pre[i].x), f2bf(pre[i].y), f2bf(pre[i].z), f2bf(pre[i].w));
            }
            if (t < 64)
                *(ushort4*)&zsb[cur][t * 4] =
                    make_ushort4(f2bf(zpre.x), f2bf(zpre.y), f2bf(zpre.z), f2bf(zpre.w));
            __syncthreads();
            if (ch < NCH - 1) {
                const float* src = Bb + (ch + 1) * KC;
#pragma unroll
                for (int i = 0; i < 8; ++i) {
                    int f = i * 1024 + t;
                    int r = f >> 6, c4 = f & 63;
                    pre[i] = *(const float4*)(src + (size_t)r * 4096 + c4 * 4);
                }
                if (t < 64) zpre = *(const float4*)(zb + (ch + 1) * KC + t * 4);
            }
#pragma unroll
            for (int ks = 0; ks < 16; ++ks) {
                bf16x8 a   = *(const bf16x8*)&As[foff_a + ks * 16];
                bf16x8 bfr = *(const bf16x8*)&As[foff_b + ks * 16];
                acc = __builtin_amdgcn_mfma_f32_32x32x16_bf16(a, bfr, acc, 0, 0, 0);
                if (diag) {
                    bf16x8 zf;
#pragma unroll
                    for (int i = 0; i < 8; ++i) zf[i] = 0;
                    if (l31 == 0) zf = *(const bf16x8*)&zsb[cur][ks * 16 + kg * 8];
                    cacc = __builtin_amdgcn_mfma_f32_32x32x16_bf16(a, zf, cacc, 0, 0, 0);
                }
            }
            // double-buffered: next iteration stages the other half of U
        }
        __syncthreads();   // all MFMA reads of U done; U becomes Gs|Bs

        // dump accumulators -> Gs (LDS), c -> cl
        float* Gs = (float*)U;
#pragma unroll
        for (int r = 0; r < 16; ++r) {
            int row = wr * 32 + (r & 3) + 8 * (r >> 2) + 4 * kg;
            Gs[row * 128 + wc * 32 + l31] = acc[r];
        }
        if (diag && l31 == 0) {
#pragma unroll
            for (int r = 0; r < 16; ++r) {
                int row = wr * 32 + (r & 3) + 8 * (r >> 2) + 4 * kg;
                cl[row] = cacc[r];
            }
        }
    }

    // ======== phase 2: BB[b] k-reduce -> Bs (LDS), fully coalesced ========
    {
        float* Bs = (float*)U + 16384;
        const float* BBb = BB + (size_t)b * 524288;
        const int grp = t >> 3, j = t & 7;    // 8 lanes per output
#pragma unroll 4
        for (int it = 0; it < 128; ++it) {
            int o = it * 128 + grp;
            float4 v = *(const float4*)(BBb + (size_t)o * 32 + j * 4);
            float s = v.x + v.y + v.z + v.w;
            s += __shfl_xor(s, 1);
            s += __shfl_xor(s, 2);
            s += __shfl_xor(s, 4);
            if (j == 0) Bs[o] = s;
        }
        // Bz reduce: zB[b] 4096 floats, same 8-lane form (one shot)
        {
            float4 v = *(const float4*)(zB + (size_t)b * 4096 + grp * 32 + j * 4);
            float s = v.x + v.y + v.z + v.w;
            s += __shfl_xor(s, 1);
            s += __shfl_xor(s, 2);
            s += __shfl_xor(s, 4);
            if (j == 0) Bz[grp] = s;
        }
        // z^2 partial
        float4 v = ((const float4*)(z + (size_t)b * 4096))[t];
        float s = v.x * v.x + v.y * v.y + v.z * v.z + v.w * v.w;
#pragma unroll
        for (int off = 32; off; off >>= 1) s += __shfl_down(s, off);
        if (lane == 0) red1[w] = s;
        if (t < 128) xs[t] = 0.f;
        __syncthreads();
        if (t == 0) {
            float tot = 0.f;
#pragma unroll
            for (int jj = 0; jj < 16; ++jj) tot += red1[jj];
            atomicAdd(Z2, tot);
        }
    }
    const float maskv = (t < 128) ? Mask[(size_t)b * 128 + t] : 0.f;
    __syncthreads();

    // ======== phase 3: 8 layers, LDS-resident matvecs ========
    const float* Gs = (const float*)U;
    const float* Bs = (const float*)U + 16384;
    const float* partf = (const float*)part;
    const int m4 = t & 31, g = t >> 5;

    for (int l = 0; l < 8; ++l) {
        // aux matvec from Bs
        {
            float4 acc = make_float4(0.f, 0.f, 0.f, 0.f);
            const float4* Bs4 = (const float4*)Bs;
#pragma unroll
            for (int i = 0; i < 4; ++i) {
                int n = g * 4 + i;
                float xv = xs[n];
                float4 mv = Bs4[n * 32 + m4];
                acc.x = fmaf(xv, mv.x, acc.x);
                acc.y = fmaf(xv, mv.y, acc.y);
                acc.z = fmaf(xv, mv.z, acc.z);
                acc.w = fmaf(xv, mv.w, acc.w);
            }
            part[g][m4] = acc;
        }
        __syncthreads();
        float outv = 0.f;
        if (t < 128) {
            float aux = -Bz[t];
            const int base = (t >> 2) * 4 + (t & 3);
#pragma unroll
            for (int g2 = 0; g2 < 32; ++g2)
                aux += partf[g2 * 132 + base];
            outv = fmaf(aux, w1[l * 128 + t], b1[l * 128 + t]) +
                   fmaf(xs[t], w2[l * 128 + t], b2[l * 128 + t]);
            atomicAdd(&ssum[l * 128 + t], outv);
            atomicAdd(&ssq[l * 128 + t], outv * outv);
        }
        lsync(cnt, 256 * (l + 1), t);
        if (t < 128) {
            float mu  = aload(&ssum[l * 128 + t]) * (1.0f / 256.0f);
            float var = aload(&ssq[l * 128 + t]) * (1.0f / 256.0f) - mu * mu;
            float inv = rsqrtf(var + 1e-5f);
            float v = (outv - mu) * inv * gamma[l * 128 + t] + beta[l * 128 + t];
            v *= maskv;
            xs[t] = fminf(1.0f, fmaxf(-1.0f, 2.0f * v));  // piecewise_clip == clamp(2v)
        }
        __syncthreads();
        // quad matvec from Gs
        {
            float4 acc = make_float4(0.f, 0.f, 0.f, 0.f);
            const float4* Gs4 = (const float4*)Gs;
#pragma unroll
            for (int i = 0; i < 4; ++i) {
                int n = g * 4 + i;
                float xv = xs[n];
                float4 mv = Gs4[n * 32 + m4];
                acc.x = fmaf(xv, mv.x, acc.x);
                acc.y = fmaf(xv, mv.y, acc.y);
                acc.z = fmaf(xv, mv.z, acc.z);
                acc.w = fmaf(xv, mv.w, acc.w);
            }
            part[g][m4] = acc;
        }
        __syncthreads();
        {
            float vq = 0.f, vl = 0.f;
            if (t < 128) {
                float gx = 0.f;
                const int base = (t >> 2) * 4 + (t & 3);
#pragma unroll
                for (int g2 = 0; g2 < 32; ++g2)
                    gx += partf[g2 * 132 + base];
                vq = xs[t] * gx;
                vl = xs[t] * cl[t];
            }
#pragma unroll
            for (int off = 32; off; off >>= 1) {
                vq += __shfl_down(vq, off);
                vl += __shfl_down(vl, off);
            }
            if (t < 128 && lane == 0) { red1[w] = vq; red2[w] = vl; }
        }
        __syncthreads();
        if (t == 0) {
            atomicAdd(&quad[l], red1[0] + red1[1]);
            atomicAdd(&lin[l],  red2[0] + red2[1]);
        }
        __syncthreads();
    }

    if (t < 128) dout[(size_t)b * 128 + t] = xs[t];
    lsync(cnt, 256 * 9, t);
    if (b == 0 && t < 8) {
        const float logs[8] = {0.0f,
                               0.6931471805599453f,
                               1.0986122886681098f,
                               1.3862943611198906f,
                               1.6094379124341003f,
                               1.7917594692280550f,
                               1.9459101490553132f,
                               2.0794415416798357f};
        float dis = (aload(&Z2[0]) - 2.0f * aload(&lin[t]) + aload(&quad[t])) * (1.0f / 32768.0f);
        dout[32768 + t] = logs[t] * dis;
    }
}

extern "C" void kernel_launch(void* const* d_in, const int* in_sizes, int n_in,
                              void* d_out, int out_size, void* d_ws, size_t ws_size,
                              hipStream_t stream) {
    (void)in_sizes; (void)n_in; (void)out_size; (void)ws_size;
    const float* BB    = (const float*)d_in[0];
    const float* zB    = (const float*)d_in[1];
    // d_in[2] = x : unused (x_est starts at zeros)
    const float* z     = (const float*)d_in[3];
    const float* Bmat  = (const float*)d_in[4];
    const float* Mask  = (const float*)d_in[5];
    const float* w1    = (const float*)d_in[6];
    const float* b1    = (const float*)d_in[7];
    const float* w2    = (const float*)d_in[8];
    const float* b2    = (const float*)d_in[9];
    const float* gamma = (const float*)d_in[10];
    const float* beta  = (const float*)d_in[11];

    float* ws   = (float*)d_ws;
    float* dout = (float*)d_out;
    int*   cnt  = (int*)(ws + OFF_CNT);
    float* ssum = ws + OFF_SSUM;
    float* ssq  = ws + OFF_SSQ;
    float* quad = ws + OFF_QUAD;
    float* lin  = ws + OFF_LIN;
    float* Z2   = ws + OFF_Z2;

    zero_kernel<<<(ZERO_COUNT + 255) / 256, 256, 0, stream>>>(ws, ZERO_COUNT);

    void* args[] = {(void*)&BB, (void*)&zB, (void*)&z, (void*)&Bmat, (void*)&Mask,
                    (void*)&w1, (void*)&b1, (void*)&w2, (void*)&b2,
                    (void*)&gamma, (void*)&beta,
                    (void*)&ssum, (void*)&ssq, (void*)&quad, (void*)&lin,
                    (void*)&Z2, (void*)&cnt, (void*)&dout};
    hipLaunchCooperativeKernel((void*)scnet_all, dim3(256), dim3(1024), args, 0, stream);
}